// Round 13
// baseline (599.566 us; speedup 1.0000x reference)
//
#include <hip/hip_runtime.h>
#include <hip/hip_bf16.h>

// Gramba (fp32 in / fp32 out): x_in = silu(x@W1+b1); x_skip = silu(x@W2+b2)
//         z = sigmoid(x_in@Wz+bz); h~ = x_in@Wh+bh
//         h = scan(h = (1-z)h + z*h~); out = (x_skip+h)@Wo + bo
// R21: gemm3k = R20's 4-phase compute + R19's BULK staging. R20 spread
//   stagelets across phases, giving SL3 only ~1 phase (<200cy) of slack
//   before its required-landing vmcnt -- below L2 latency. Now all 4
//   stagelets of step t+1 issue at phase 0 of step t (buffer free: step
//   t-1 readers retired at its trailing barrier); vmcnt(8) at phase 0
//   retires step t's 8 loads, keeps t+1's 8 in flight (never 0 except
//   final step); every load gets a full K-step of slack.
//   Everything else == R20 (567.9 us): gemm4<0> input, gemm_bt64<3>
//   output, R9 scan, fused prep.
//
// Workspace layout (183 MiB):
//   [0,32)    rawzh chunk (bf16, 4096x4096)   [xb overlays [0,16) before use]
//   [32,33)   carry (fp32 h state, 4x2048)
//   [33,97)   xin   (bf16, 16384x2048)
//   [97,161)  xskip (bf16; scan overwrites with s = x_skip+h)
//   [161,165) Wt12  (bf16 [4096][512])
//   [165,181) Wtzh  (bf16 [4096][2048])
//   [181,183) Wto   (bf16 [512][2048])

typedef __bf16 bf16x8 __attribute__((ext_vector_type(8)));
typedef __bf16 bf16x4 __attribute__((ext_vector_type(4)));
typedef float  f32x4  __attribute__((ext_vector_type(4)));

#define DEVINL __device__ __forceinline__

DEVINL void async_ld16(const __bf16* g, __bf16* l) {
    __builtin_amdgcn_global_load_lds(
        (const __attribute__((address_space(1))) void*)g,
        (__attribute__((address_space(3))) void*)l, 16, 0, 0);
}

DEVINL float fsigmoid(float v) { return 1.0f / (1.0f + __expf(-v)); }

// ---------------------------------------------------------------------------
// gemm4: 128x256 tile, 512 threads (8 waves, 2M x 4N, 64x64/wave), BK=32,
// dual-buffered 48 KiB LDS (3 blk/CU), depth-1 counted-vmcnt(3) schedule.
// Input GEMM (K=512). MODE 0: dual split-silu -> bf16 out/out2.
// ---------------------------------------------------------------------------
template <int MODE>
__global__ __launch_bounds__(512, 4)
void gemm4(const __bf16* __restrict__ A, const __bf16* __restrict__ Bt,
           const float* __restrict__ bias, const float* __restrict__ bias2,
           void* __restrict__ out, void* __restrict__ out2, int N, int K,
           int bps, int seg_stride, int row_off)
{
    struct KL { __bf16 A[128 * 32]; __bf16 B[256 * 32]; };   // 24 KiB
    __shared__ union SM4 {
        KL kl[2];                    // 48 KiB
        __bf16 ct[64 * 264];         // 33 KiB epilogue tile (64 x 256, pad 8)
    } sm;
    const int tid = threadIdx.x;                 // 0..511
    const int bx = blockIdx.x;
    const int seg = bx / bps;
    const int within = bx - seg * bps;
    const int gm0 = row_off + seg * seg_stride + within * 128;  // A row base
    const int om0 = bx * 128;                                   // out row base
    const int n0 = blockIdx.y * 256;

    const int rA = tid >> 2,         kA = (tid & 3) ^ ((tid >> 3) & 3);
    const int c0 = tid, c1 = tid + 512;
    const int rB0 = c0 >> 2,         kB0 = (c0 & 3) ^ ((c0 >> 3) & 3);
    const int rB1 = c1 >> 2,         kB1 = (c1 & 3) ^ ((c1 >> 3) & 3);
    const __bf16* Ag  = A  + (size_t)(gm0 + rA)  * K + kA  * 8;
    const __bf16* Bg0 = Bt + (size_t)(n0 + rB0) * K + kB0 * 8;
    const __bf16* Bg1 = Bt + (size_t)(n0 + rB1) * K + kB1 * 8;

    const int lane = tid & 63;
    const int wave = tid >> 6;
    const int wm = wave >> 2;        // 0..1  (M half: 64 rows)
    const int wn = wave & 3;         // 0..3  (N quarter: 64 cols)
    const int quad = lane >> 4;
    const int r = lane & 15;
    const int swz = (quad ^ ((r >> 1) & 3)) * 8;

    f32x4 acc[4][4] = {};

    const int T = K >> 5;            // K-tiles of 32 (T=16 for K=512)

    auto stage = [&](int t, int b) {
        const int kt = t << 5;
        async_ld16(Ag  + kt, sm.kl[b].A + tid * 8);
        async_ld16(Bg0 + kt, sm.kl[b].B + c0 * 8);
        async_ld16(Bg1 + kt, sm.kl[b].B + c1 * 8);
    };

    stage(0, 0);

    for (int t = 0; t < T; ++t) {
        const int cur = t & 1;
        if (t + 1 < T) {
            stage(t + 1, cur ^ 1);   // 3 loads -> 6 outstanding
            asm volatile("s_waitcnt vmcnt(3)\n\ts_barrier" ::: "memory");
        } else {
            asm volatile("s_waitcnt vmcnt(0)\n\ts_barrier" ::: "memory");
        }

        const __bf16* ap = sm.kl[cur].A + (wm * 64 + r) * 32 + swz;
        const __bf16* bp = sm.kl[cur].B + (wn * 64 + r) * 32 + swz;
        bf16x8 af[4], bf_[4];
#pragma unroll
        for (int m = 0; m < 4; ++m) af[m] = *(const bf16x8*)(ap + m * 512);
#pragma unroll
        for (int n = 0; n < 4; ++n) bf_[n] = *(const bf16x8*)(bp + n * 512);

        __builtin_amdgcn_s_setprio(1);
#pragma unroll
        for (int m = 0; m < 4; ++m)
#pragma unroll
            for (int n = 0; n < 4; ++n)
                acc[m][n] = __builtin_amdgcn_mfma_f32_16x16x32_bf16(
                    af[m], bf_[n], acc[m][n], 0, 0, 0);
        __builtin_amdgcn_s_setprio(0);

        asm volatile("s_waitcnt lgkmcnt(0)\n\ts_barrier" ::: "memory");
    }

    // Epilogue. C/D layout (m89): col = lane&15, row = (lane>>4)*4 + reg.
    const bool lo = n0 < 2048;       // tile-uniform (n0 multiple of 256)
    __bf16* dst;
    int cb;
    size_t stride;
    if (MODE == 0) {
        dst = lo ? (__bf16*)out : (__bf16*)out2;
        cb = lo ? n0 : n0 - 2048;
        stride = 2048;
    } else {
        dst = (__bf16*)out;
        cb = n0;
        stride = (size_t)N;
    }
    float bvj[4];
#pragma unroll
    for (int nf = 0; nf < 4; ++nf) {
        const int gc = n0 + wn * 64 + nf * 16 + r;
        bvj[nf] = lo ? bias[gc] : bias2[gc - 2048];
    }

#pragma unroll
    for (int p = 0; p < 2; ++p) {
        if (wm == p) {
#pragma unroll
            for (int mm = 0; mm < 4; ++mm)
#pragma unroll
                for (int nf = 0; nf < 4; ++nf)
#pragma unroll
                    for (int k = 0; k < 4; ++k) {
                        const float v = acc[mm][nf][k] + bvj[nf];
                        const __bf16 o = (MODE == 0) ? (__bf16)(v * fsigmoid(v))
                                                     : (__bf16)v;
                        sm.ct[(mm * 16 + quad * 4 + k) * 264 +
                              (wn * 64 + nf * 16 + r)] = o;
                    }
        }
        __syncthreads();
#pragma unroll
        for (int q = 0; q < 4; ++q) {
            const int chunk = q * 512 + tid;      // 0..2047
            const int trow = chunk >> 5;          // 0..63
            const int tc = (chunk & 31) * 8;      // bf16 col, x8 chunk
            const bf16x8 vv = *(const bf16x8*)(sm.ct + trow * 264 + tc);
            *(bf16x8*)(dst + (size_t)(om0 + p * 64 + trow) * stride + cb + tc) = vv;
        }
        __syncthreads();
    }
}

// ---------------------------------------------------------------------------
// gemm3k (R21): 256x256 tile, BK=64, 512 threads (8 waves, 2M x 4N,
// 128x64/wave), dual-buffered 128 KiB LDS. 4-phase compute interleave +
// BULK staging: all 8 loads of step t+1 issue at phase 0 of step t;
// vmcnt(8) gives every load a full K-step of slack (never 0 in main loop).
// Recurrent GEMMs only (K=2048 -> T=32). MODE 4: bf16 out, dual bias.
// LDS chunk map: slot s -> row s>>3, stored-pos s&7 holds k-chunk
// (s&7)^(row&7); reader of chunk c at row reads pos c^(row&7).
// ---------------------------------------------------------------------------
template <int MODE>
__global__ __launch_bounds__(512, 2)
void gemm3k(const __bf16* __restrict__ A, const __bf16* __restrict__ Bt,
            const float* __restrict__ bias, const float* __restrict__ bias2,
            void* __restrict__ out, void* __restrict__ out2, int N, int K,
            int bps, int seg_stride, int row_off)
{
    struct KL { __bf16 A[256 * 64]; __bf16 B[256 * 64]; };   // 64 KiB
    __shared__ union SM3K {
        KL kl[2];                    // 128 KiB
        __bf16 ct[64 * 264];         // 33 KiB epilogue tile (64 x 256, pad 8)
    } sm;
    const int tid = threadIdx.x;                 // 0..511
    const int bx = blockIdx.x;
    const int seg = bx / bps;
    const int within = bx - seg * bps;
    const int gm0 = row_off + seg * seg_stride + within * 256;  // A row base
    const int om0 = bx * 256;                                   // out row base
    const int n0 = blockIdx.y * 256;

    // Staging: each 256x64 half = 2048 chunks; 4 per thread (s = tid + 512j).
    int rA[4], kA[4];
#pragma unroll
    for (int j = 0; j < 4; ++j) {
        const int s = tid + 512 * j;
        rA[j] = s >> 3;
        kA[j] = (s & 7) ^ (rA[j] & 7);
    }
    const __bf16* Agp[4];
    const __bf16* Bgp[4];
#pragma unroll
    for (int j = 0; j < 4; ++j) {
        Agp[j] = A  + (size_t)(gm0 + rA[j]) * K + kA[j] * 8;
        Bgp[j] = Bt + (size_t)(n0 + rA[j]) * K + kA[j] * 8;
    }

    const int lane = tid & 63;
    const int wave = tid >> 6;
    const int wm = wave >> 2;        // 0..1  (M half: 128 rows)
    const int wn = wave & 3;         // 0..3  (N quarter: 64 cols)
    const int quad = lane >> 4;
    const int r = lane & 15;

    f32x4 acc[8][4] = {};

    const int T = K >> 6;            // K-tiles of 64 (T=32 for K=2048)

    auto stage = [&](int t, int b) {
        const int kt = t << 6;
#pragma unroll
        for (int j = 0; j < 4; ++j)
            async_ld16(Agp[j] + kt, sm.kl[b].A + (tid + 512 * j) * 8);
#pragma unroll
        for (int j = 0; j < 4; ++j)
            async_ld16(Bgp[j] + kt, sm.kl[b].B + (tid + 512 * j) * 8);
    };

    stage(0, 0);                     // 8 outstanding

    const int swz0 = ((0 * 4 + quad) ^ (r & 7)) * 8;
    const int swz1 = ((1 * 4 + quad) ^ (r & 7)) * 8;

    for (int t = 0; t < T; ++t) {
        const int cur = t & 1;
        const bool pre = (t + 1) < T;
        const __bf16* apb = sm.kl[cur].A + (wm * 128 + r) * 64;
        const __bf16* bpb = sm.kl[cur].B + (wn * 64 + r) * 64;

        bf16x8 bfr[2][4];            // B frags [kslot][nf], live across phases

        // ---- phase 0: bulk stage(t+1), vmcnt(8)+publish, A m=0,1 + all B,
        //      16 MFMA ----
        if (pre) {
            // Buffer cur^1 free: step t-1 readers retired at its trailing
            // barrier (precedes these issues in every wave's program order).
            stage(t + 1, cur ^ 1);
            // outstanding: 8(t) + 8(t+1) -> retire step t's 8, keep 8 flying.
            asm volatile("s_waitcnt vmcnt(8)" ::: "memory");
        } else {
            asm volatile("s_waitcnt vmcnt(0)" ::: "memory");
        }
        __builtin_amdgcn_s_barrier();            // publication of step t
        {
            bf16x8 a00 = *(const bf16x8*)(apb + 0 * 1024 + swz0);
            bf16x8 a01 = *(const bf16x8*)(apb + 0 * 1024 + swz1);
            bf16x8 a10 = *(const bf16x8*)(apb + 1 * 1024 + swz0);
            bf16x8 a11 = *(const bf16x8*)(apb + 1 * 1024 + swz1);
#pragma unroll
            for (int n = 0; n < 4; ++n) {
                bfr[0][n] = *(const bf16x8*)(bpb + n * 1024 + swz0);
                bfr[1][n] = *(const bf16x8*)(bpb + n * 1024 + swz1);
            }
            asm volatile("s_waitcnt lgkmcnt(0)" ::: "memory");
            __builtin_amdgcn_s_setprio(1);
#pragma unroll
            for (int n = 0; n < 4; ++n) {
                acc[0][n] = __builtin_amdgcn_mfma_f32_16x16x32_bf16(a00, bfr[0][n], acc[0][n], 0, 0, 0);
                acc[0][n] = __builtin_amdgcn_mfma_f32_16x16x32_bf16(a01, bfr[1][n], acc[0][n], 0, 0, 0);
                acc[1][n] = __builtin_amdgcn_mfma_f32_16x16x32_bf16(a10, bfr[0][n], acc[1][n], 0, 0, 0);
                acc[1][n] = __builtin_amdgcn_mfma_f32_16x16x32_bf16(a11, bfr[1][n], acc[1][n], 0, 0, 0);
            }
            __builtin_amdgcn_s_setprio(0);
        }
        __builtin_amdgcn_s_barrier();

        // ---- phases 1..3: read A m=2p,2p+1, 16 MFMA ----
#pragma unroll
        for (int p = 1; p < 4; ++p) {
            bf16x8 a00 = *(const bf16x8*)(apb + (2 * p    ) * 1024 + swz0);
            bf16x8 a01 = *(const bf16x8*)(apb + (2 * p    ) * 1024 + swz1);
            bf16x8 a10 = *(const bf16x8*)(apb + (2 * p + 1) * 1024 + swz0);
            bf16x8 a11 = *(const bf16x8*)(apb + (2 * p + 1) * 1024 + swz1);
            __builtin_amdgcn_s_barrier();        // (a) scheduling
            asm volatile("s_waitcnt lgkmcnt(0)" ::: "memory");
            __builtin_amdgcn_s_setprio(1);
#pragma unroll
            for (int n = 0; n < 4; ++n) {
                acc[2 * p][n]     = __builtin_amdgcn_mfma_f32_16x16x32_bf16(a00, bfr[0][n], acc[2 * p][n], 0, 0, 0);
                acc[2 * p][n]     = __builtin_amdgcn_mfma_f32_16x16x32_bf16(a01, bfr[1][n], acc[2 * p][n], 0, 0, 0);
                acc[2 * p + 1][n] = __builtin_amdgcn_mfma_f32_16x16x32_bf16(a10, bfr[0][n], acc[2 * p + 1][n], 0, 0, 0);
                acc[2 * p + 1][n] = __builtin_amdgcn_mfma_f32_16x16x32_bf16(a11, bfr[1][n], acc[2 * p + 1][n], 0, 0, 0);
            }
            __builtin_amdgcn_s_setprio(0);
            __builtin_amdgcn_s_barrier();        // (b)
        }
    }

    // Epilogue. C/D layout (m89). 4 passes of 64 rows through ct (stride 264).
    __syncthreads();

    const bool lo = n0 < 2048;       // tile-uniform (n0 multiple of 256)
    __bf16* dst = (__bf16*)out;
    const int cb = n0;
    const size_t stride = (size_t)N;
    float bvj[4];
#pragma unroll
    for (int nf = 0; nf < 4; ++nf) {
        const int gc = n0 + wn * 64 + nf * 16 + r;
        bvj[nf] = lo ? bias[gc] : bias2[gc - 2048];
    }

#pragma unroll
    for (int p = 0; p < 4; ++p) {
        if (wm == (p >> 1)) {
            const int mb = (p & 1) * 4;
#pragma unroll
            for (int mm = 0; mm < 4; ++mm)
#pragma unroll
                for (int nf = 0; nf < 4; ++nf)
#pragma unroll
                    for (int k = 0; k < 4; ++k) {
                        const float v = acc[mb + mm][nf][k] + bvj[nf];
                        sm.ct[(mm * 16 + quad * 4 + k) * 264 +
                              (wn * 64 + nf * 16 + r)] = (__bf16)v;
                    }
        }
        __syncthreads();
#pragma unroll
        for (int q = 0; q < 4; ++q) {
            const int chunk = q * 512 + tid;      // 0..2047
            const int trow = chunk >> 5;          // 0..63
            const int tc = (chunk & 31) * 8;      // bf16 col, x8 chunk
            const bf16x8 vv = *(const bf16x8*)(sm.ct + trow * 264 + tc);
            *(bf16x8*)(dst + (size_t)(om0 + p * 64 + trow) * stride + cb + tc) = vv;
        }
        __syncthreads();
    }
}

// ---------------------------------------------------------------------------
// gemm_bt64: 128x128 tile, BK=64, 256 threads (4 waves, 64x64/wave), dual
// 64 KiB LDS, counted vmcnt(8). Output GEMM (K=2048, T=32). MODE 3: fp32.
// ---------------------------------------------------------------------------
template <int MODE>
__global__ __launch_bounds__(256)
void gemm_bt64(const __bf16* __restrict__ A, const __bf16* __restrict__ Bt,
               const float* __restrict__ bias, const float* __restrict__ bias2,
               void* __restrict__ out, void* __restrict__ out2, int N, int K,
               int bps, int seg_stride, int row_off)
{
    struct KL64 { __bf16 A[128 * 64]; __bf16 B[128 * 64]; };   // 32 KiB
    __shared__ union SMB64 {
        KL64 kl[2];                  // 64 KiB
        float  ctf[32 * 132];        // 17 KiB fp32 epilogue tile
    } sm;
    const int tid = threadIdx.x;                 // 0..255
    const int bx = blockIdx.x;
    const int seg = bx / bps;
    const int within = bx - seg * bps;
    const int gm0 = row_off + seg * seg_stride + within * 128;  // A row base
    const int om0 = bx * 128;                                   // out row base
    const int n0 = blockIdx.y * 128;

    int rS[4], kS[4];
#pragma unroll
    for (int j = 0; j < 4; ++j) {
        const int s = tid + 256 * j;
        rS[j] = s >> 3;
        kS[j] = (s & 7) ^ (rS[j] & 7);
    }
    const __bf16* Agp[4];
    const __bf16* Bgp[4];
#pragma unroll
    for (int j = 0; j < 4; ++j) {
        Agp[j] = A  + (size_t)(gm0 + rS[j]) * K + kS[j] * 8;
        Bgp[j] = Bt + (size_t)(n0 + rS[j]) * K + kS[j] * 8;
    }

    const int lane = tid & 63;
    const int wave = tid >> 6;
    const int wrow = (wave >> 1) * 64;
    const int wcol = (wave & 1) * 64;
    const int quad = lane >> 4;
    const int r = lane & 15;

    f32x4 acc[4][4] = {};

    const int T = K >> 6;            // K-tiles of 64 (T=32 for K=2048)

    auto stage = [&](int t, int b) {
        const int kt = t << 6;
#pragma unroll
        for (int j = 0; j < 4; ++j)
            async_ld16(Agp[j] + kt, sm.kl[b].A + (tid + 256 * j) * 8);
#pragma unroll
        for (int j = 0; j < 4; ++j)
            async_ld16(Bgp[j] + kt, sm.kl[b].B + (tid + 256 * j) * 8);
    };

    stage(0, 0);                     // 8 outstanding

    const int swz0 = ((0 * 4 + quad) ^ (r & 7)) * 8;
    const int swz1 = ((1 * 4 + quad) ^ (r & 7)) * 8;

    for (int t = 0; t < T; ++t) {
        const int cur = t & 1;
        if (t + 1 < T) {
            stage(t + 1, cur ^ 1);   // 16 outstanding
            asm volatile("s_waitcnt vmcnt(8)\n\ts_barrier" ::: "memory");
        } else {
            asm volatile("s_waitcnt vmcnt(0)\n\ts_barrier" ::: "memory");
        }

        const __bf16* apb = sm.kl[cur].A + (wrow + r) * 64;
        const __bf16* bpb = sm.kl[cur].B + (wcol + r) * 64;

#pragma unroll
        for (int ks = 0; ks < 2; ++ks) {
            const int swz = ks ? swz1 : swz0;
            bf16x8 af[4], bf_[4];
#pragma unroll
            for (int m = 0; m < 4; ++m)
                af[m] = *(const bf16x8*)(apb + m * 1024 + swz);
#pragma unroll
            for (int n = 0; n < 4; ++n)
                bf_[n] = *(const bf16x8*)(bpb + n * 1024 + swz);

            __builtin_amdgcn_s_setprio(1);
#pragma unroll
            for (int m = 0; m < 4; ++m)
#pragma unroll
                for (int n = 0; n < 4; ++n)
                    acc[m][n] = __builtin_amdgcn_mfma_f32_16x16x32_bf16(
                        af[m], bf_[n], acc[m][n], 0, 0, 0);
            __builtin_amdgcn_s_setprio(0);
        }

        asm volatile("s_waitcnt lgkmcnt(0)\n\ts_barrier" ::: "memory");
    }

    // fp32 staged epilogue: 4 passes of 32 rows through [32][132] LDS.
    {
        float bvj[4];
#pragma unroll
        for (int j = 0; j < 4; ++j)
            bvj[j] = bias[n0 + wcol + j * 16 + r];
#pragma unroll
        for (int p = 0; p < 4; ++p) {
#pragma unroll
            for (int j = 0; j < 4; ++j)
#pragma unroll
                for (int k = 0; k < 4; ++k)
                    sm.ctf[((wave >> 1) * 16 + quad * 4 + k) * 132 +
                           (wcol + j * 16 + r)] = acc[p][j][k] + bvj[j];
            __syncthreads();
#pragma unroll
            for (int q = 0; q < 4; ++q) {
                const int chunk = q * 256 + tid;      // 0..1023
                const int trow = chunk >> 5;          // 0..31
                const int tc4 = (chunk & 31) * 4;     // fp32 col, x4 chunk
                const f32x4 vv = *(const f32x4*)(sm.ctf + trow * 132 + tc4);
                const int grow = om0 + (trow >> 4) * 64 + p * 16 + (trow & 15);
                *(f32x4*)((float*)out + (size_t)grow * N + n0 + tc4) = vv;
            }
            __syncthreads();
        }
    }
}

// Parallel minGRU scan over one chunk, on raw pre-activations:
// z = sigmoid(raw_z), b = z * raw_h, h = (1-z)h + b.
// raw is [B*CS][4096] (z cols 0..2047, h cols 2048..4095).
#define SSEG 32
#define SCOLS 32
__global__ __launch_bounds__(1024)
void scan_kernel(const __bf16* __restrict__ raw, __bf16* __restrict__ xskip,
                 float* __restrict__ carry, int CS, int S, int t0, int first)
{
    __shared__ float Als[SSEG][SCOLS];
    __shared__ float Bls[SSEG][SCOLS];
    const int lane = threadIdx.x & (SCOLS - 1);   // col within group
    const int w = threadIdx.x >> 5;               // segment 0..31
    const int nb8 = gridDim.x >> 3;
    const int lin = (blockIdx.x & 7) * nb8 + (blockIdx.x >> 3);
    const int gpb = 2048 / SCOLS;                 // 64 groups per batch
    const int batch = lin / gpb;
    const int col = (lin - batch * gpb) * SCOLS + lane;
    const int L = CS / SSEG;                      // 32 (CS always 1024)
    const int tbeg = w * L;

    const size_t rbase = ((size_t)batch * CS + tbeg) * 4096 + col;

    float av[32], bv[32];
    float A = 1.0f, Bv = 0.0f;
    {
        size_t idx = rbase;
#pragma unroll
        for (int t = 0; t < 32; ++t, idx += 4096) {
            const float z = fsigmoid((float)raw[idx]);
            const float b = z * (float)raw[idx + 2048];
            const float a = 1.0f - z;
            av[t] = a;
            bv[t] = b;
            Bv = a * Bv + b;
            A *= a;
        }
    }
    Als[w][lane] = A;
    Bls[w][lane] = Bv;
    __syncthreads();

    const int ch = batch * 2048 + col;
    float h = first ? 0.0f : carry[ch];
    for (int s = 0; s < w; ++s)
        h = Als[s][lane] * h + Bls[s][lane];
    if (w == SSEG - 1)
        carry[ch] = A * h + Bv;

    {
        size_t gidx = ((size_t)batch * S + t0 + tbeg) * 2048 + col;
#pragma unroll
        for (int t = 0; t < 32; ++t, gidx += 2048) {
            h = av[t] * h + bv[t];
            xskip[gidx] = (__bf16)((float)xskip[gidx] + h);
        }
    }
}

// ---------------------------------------------------------------------------
// prep_kernel: fused prepass. Block-range dispatch (branch is block-uniform):
//   [0, 8192)            conv x fp32 -> xb bf16 (float4 granularity)
//   [8192, 8192+2048)    Wt12: transpose W_in1/W_in2 (K=512,  N=2048), z=hi
//   [+2048, +2048+8192)  Wtzh: transpose W_z/W_h    (K=2048, N=2048), z=hi
//   [.., +1024)          Wto:  transpose W_out      (K=2048, N=512)
// ---------------------------------------------------------------------------
__global__ __launch_bounds__(256)
void prep_kernel(const float* __restrict__ x, __bf16* __restrict__ xb,
                 const float* __restrict__ W_in1, const float* __restrict__ W_in2,
                 __bf16* __restrict__ Wt12,
                 const float* __restrict__ W_z, const float* __restrict__ W_h,
                 __bf16* __restrict__ Wtzh,
                 const float* __restrict__ W_out, __bf16* __restrict__ Wto)
{
    __shared__ float tile[32][33];
    int bid = blockIdx.x;
    if (bid < 8192) {                      // conv: 8192*256 float4 = M*H
        const int i = bid * 256 + threadIdx.x;
        const float4 v = ((const float4*)x)[i];
        bf16x4 o;
        o[0] = (__bf16)v.x; o[1] = (__bf16)v.y;
        o[2] = (__bf16)v.z; o[3] = (__bf16)v.w;
        ((bf16x4*)xb)[i] = o;
        return;
    }
    bid -= 8192;
    const float* W;
    __bf16* dst;
    int K, N, nb, kb;
    if (bid < 2048) {                      // Wt12 (K=512, N=2048)
        const int z = bid >> 10, rem = bid & 1023;
        W = z ? W_in2 : W_in1;
        dst = Wt12 + (size_t)z * 512 * 2048;
        K = 512; N = 2048;
        nb = (rem & 63) * 32; kb = (rem >> 6) * 32;   // rem = kb*64 + nb
    } else if (bid < 2048 + 8192) {        // Wtzh (K=2048, N=2048)
        const int b2 = bid - 2048;
        const int z = b2 >> 12, rem = b2 & 4095;
        W = z ? W_h : W_z;
        dst = Wtzh + (size_t)z * 2048 * 2048;
        K = 2048; N = 2048;
        nb = (rem & 63) * 32; kb = (rem >> 6) * 32;
    } else {                               // Wto (K=2048, N=512)
        const int b3 = bid - (2048 + 8192);
        W = W_out; dst = Wto;
        K = 2048; N = 512;
        nb = (b3 & 15) * 32; kb = (b3 >> 4) * 32;
    }
    const int tx = threadIdx.x & 31;
    const int ty = threadIdx.x >> 5;
#pragma unroll
    for (int i = 0; i < 32; i += 8)
        tile[ty + i][tx] = W[(size_t)(kb + ty + i) * N + nb + tx];
    __syncthreads();
#pragma unroll
    for (int i = 0; i < 32; i += 8)
        dst[(size_t)(nb + ty + i) * K + kb + tx] = (__bf16)tile[tx][ty + i];
}

extern "C" void kernel_launch(void* const* d_in, const int* in_sizes, int n_in,
                              void* d_out, int out_size, void* d_ws, size_t ws_size,
                              hipStream_t stream)
{
    const float* x     = (const float*)d_in[0];
    const float* W_in1 = (const float*)d_in[1];
    const float* b_in1 = (const float*)d_in[2];
    const float* W_in2 = (const float*)d_in[3];
    const float* b_in2 = (const float*)d_in[4];
    const float* W_z   = (const float*)d_in[5];
    const float* b_z   = (const float*)d_in[6];
    const float* W_h   = (const float*)d_in[7];
    const float* b_h   = (const float*)d_in[8];
    const float* W_out = (const float*)d_in[9];
    const float* b_out = (const float*)d_in[10];

    const int B = 4, S = 4096, H = 512, E = 2048;
    const int M = B * S;        // 16384
    const int CS = 1024;        // chunk length
    const int NC = S / CS;      // 4 chunks
    const int MC = B * CS;      // 4096 rows per chunk

    const size_t MiB = 1024 * 1024;
    const size_t NEEDED = 183 * MiB;
    if (ws_size < NEEDED) return;

    char* ws = (char*)d_ws;
    __bf16* xb    = (__bf16*)(ws + 0);        // overlaid by rawzh after use
    __bf16* rawzh = (__bf16*)(ws + 0);
    float*  carry = (float*) (ws + 32 * MiB);
    __bf16* xin   = (__bf16*)(ws + 33 * MiB);
    __bf16* xskip = (__bf16*)(ws + 97 * MiB);
    __bf16* Wt12  = (__bf16*)(ws + 161 * MiB);
    __bf16* Wtzh  = (__bf16*)(ws + 165 * MiB);
    __bf16* Wto   = (__bf16*)(ws + 181 * MiB);

    // Fused prepass: conv + all 5 weight transposes in one launch.
    prep_kernel<<<8192 + 2048 + 8192 + 1024, 256, 0, stream>>>(
        x, xb, W_in1, W_in2, Wt12, W_z, W_h, Wtzh, W_out, Wto);

    // Merged input GEMM: N=4096 (W1|W2), split-silu epilogue -> xin / xskip
    // gemm4 128x256 tiles, BK=32, 3 blk/CU: grid 128 x 16.
    gemm4<0><<<dim3(M / 128, 2 * E / 256), 512, 0, stream>>>(
        xb, Wt12, b_in1, b_in2, xin, xskip, 2 * E, H, M / 128, 0, 0);

    // Recurrent stage, chunked over S (rawzh overlays dead xb)
    // gemm3k (4-phase + bulk stage) 256^2, BK=64: grid 16x16 = 256, T=32.
    for (int c = 0; c < NC; ++c) {
        const int row_off = c * CS;
        gemm3k<4><<<dim3(MC / 256, 2 * E / 256), 512, 0, stream>>>(
            xin, Wtzh, b_z, b_h, rawzh, nullptr, 2 * E, E, CS / 256, S, row_off);
        scan_kernel<<<(B * E) / SCOLS, 1024, 0, stream>>>(
            rawzh, xskip, carry, CS, S, row_off, c == 0);
    }

    // Output GEMM (full M), fp32 out -- BK=64 (K=2048, T=32), grid 512 = 2/CU.
    gemm_bt64<3><<<dim3(M / 128, H / 128), 256, 0, stream>>>(
        xskip, Wto, b_out, nullptr, (float*)d_out, nullptr, H, E, M / 128, 0, 0);
}

// Round 14
// 578.012 us; speedup vs baseline: 1.0373x; 1.0373x over previous
//
#include <hip/hip_runtime.h>
#include <hip/hip_bf16.h>

// Gramba (fp32 in / fp32 out): x_in = silu(x@W1+b1); x_skip = silu(x@W2+b2)
//         z = sigmoid(x_in@Wz+bz); h~ = x_in@Wh+bh
//         h = scan(h = (1-z)h + z*h~); out = (x_skip+h)@Wo + bo
// R22: (a) REVERT gemm3k to R20's measured-best loop {4-phase + spread
//   stagelets + vmcnt(2)} -- R21's bulk-staging variant cost +8 us/dispatch
//   (64-load burst at phase 0 contends with the vmcnt + heaviest ds_read
//   phase). Ledger: R19 monolithic+bulk = G; R20 = G-1.7; R21 = G+6.2.
//   (b) NEW: __builtin_nontemporal_store on all three GEMM epilogues.
//   gemm4 FETCH=61MB vs ~20MB ideal: its own 134MB write stream evicts xb
//   from L3 between column-tile re-reads (same for gemm3k/xin, bt64/d_out).
//   nt stores keep L3 clean -> staged loads hit L3/L2 (~250cy) not HBM
//   (~900cy) -> depth-1 prefetch slack suffices.
//   Everything else == R20 (567.9 us).
//
// Workspace layout (183 MiB):
//   [0,32)    rawzh chunk (bf16, 4096x4096)   [xb overlays [0,16) before use]
//   [32,33)   carry (fp32 h state, 4x2048)
//   [33,97)   xin   (bf16, 16384x2048)
//   [97,161)  xskip (bf16; scan overwrites with s = x_skip+h)
//   [161,165) Wt12  (bf16 [4096][512])
//   [165,181) Wtzh  (bf16 [4096][2048])
//   [181,183) Wto   (bf16 [512][2048])

typedef __bf16 bf16x8 __attribute__((ext_vector_type(8)));
typedef __bf16 bf16x4 __attribute__((ext_vector_type(4)));
typedef float  f32x4  __attribute__((ext_vector_type(4)));

#define DEVINL __device__ __forceinline__

DEVINL void async_ld16(const __bf16* g, __bf16* l) {
    __builtin_amdgcn_global_load_lds(
        (const __attribute__((address_space(1))) void*)g,
        (__attribute__((address_space(3))) void*)l, 16, 0, 0);
}

DEVINL float fsigmoid(float v) { return 1.0f / (1.0f + __expf(-v)); }

// ---------------------------------------------------------------------------
// gemm4: 128x256 tile, 512 threads (8 waves, 2M x 4N, 64x64/wave), BK=32,
// dual-buffered 48 KiB LDS (3 blk/CU), depth-1 counted-vmcnt(3) schedule.
// Input GEMM (K=512). MODE 0: dual split-silu -> bf16 out/out2.
// ---------------------------------------------------------------------------
template <int MODE>
__global__ __launch_bounds__(512, 4)
void gemm4(const __bf16* __restrict__ A, const __bf16* __restrict__ Bt,
           const float* __restrict__ bias, const float* __restrict__ bias2,
           void* __restrict__ out, void* __restrict__ out2, int N, int K,
           int bps, int seg_stride, int row_off)
{
    struct KL { __bf16 A[128 * 32]; __bf16 B[256 * 32]; };   // 24 KiB
    __shared__ union SM4 {
        KL kl[2];                    // 48 KiB
        __bf16 ct[64 * 264];         // 33 KiB epilogue tile (64 x 256, pad 8)
    } sm;
    const int tid = threadIdx.x;                 // 0..511
    const int bx = blockIdx.x;
    const int seg = bx / bps;
    const int within = bx - seg * bps;
    const int gm0 = row_off + seg * seg_stride + within * 128;  // A row base
    const int om0 = bx * 128;                                   // out row base
    const int n0 = blockIdx.y * 256;

    const int rA = tid >> 2,         kA = (tid & 3) ^ ((tid >> 3) & 3);
    const int c0 = tid, c1 = tid + 512;
    const int rB0 = c0 >> 2,         kB0 = (c0 & 3) ^ ((c0 >> 3) & 3);
    const int rB1 = c1 >> 2,         kB1 = (c1 & 3) ^ ((c1 >> 3) & 3);
    const __bf16* Ag  = A  + (size_t)(gm0 + rA)  * K + kA  * 8;
    const __bf16* Bg0 = Bt + (size_t)(n0 + rB0) * K + kB0 * 8;
    const __bf16* Bg1 = Bt + (size_t)(n0 + rB1) * K + kB1 * 8;

    const int lane = tid & 63;
    const int wave = tid >> 6;
    const int wm = wave >> 2;        // 0..1  (M half: 64 rows)
    const int wn = wave & 3;         // 0..3  (N quarter: 64 cols)
    const int quad = lane >> 4;
    const int r = lane & 15;
    const int swz = (quad ^ ((r >> 1) & 3)) * 8;

    f32x4 acc[4][4] = {};

    const int T = K >> 5;            // K-tiles of 32 (T=16 for K=512)

    auto stage = [&](int t, int b) {
        const int kt = t << 5;
        async_ld16(Ag  + kt, sm.kl[b].A + tid * 8);
        async_ld16(Bg0 + kt, sm.kl[b].B + c0 * 8);
        async_ld16(Bg1 + kt, sm.kl[b].B + c1 * 8);
    };

    stage(0, 0);

    for (int t = 0; t < T; ++t) {
        const int cur = t & 1;
        if (t + 1 < T) {
            stage(t + 1, cur ^ 1);   // 3 loads -> 6 outstanding
            asm volatile("s_waitcnt vmcnt(3)\n\ts_barrier" ::: "memory");
        } else {
            asm volatile("s_waitcnt vmcnt(0)\n\ts_barrier" ::: "memory");
        }

        const __bf16* ap = sm.kl[cur].A + (wm * 64 + r) * 32 + swz;
        const __bf16* bp = sm.kl[cur].B + (wn * 64 + r) * 32 + swz;
        bf16x8 af[4], bf_[4];
#pragma unroll
        for (int m = 0; m < 4; ++m) af[m] = *(const bf16x8*)(ap + m * 512);
#pragma unroll
        for (int n = 0; n < 4; ++n) bf_[n] = *(const bf16x8*)(bp + n * 512);

        __builtin_amdgcn_s_setprio(1);
#pragma unroll
        for (int m = 0; m < 4; ++m)
#pragma unroll
            for (int n = 0; n < 4; ++n)
                acc[m][n] = __builtin_amdgcn_mfma_f32_16x16x32_bf16(
                    af[m], bf_[n], acc[m][n], 0, 0, 0);
        __builtin_amdgcn_s_setprio(0);

        asm volatile("s_waitcnt lgkmcnt(0)\n\ts_barrier" ::: "memory");
    }

    // Epilogue. C/D layout (m89): col = lane&15, row = (lane>>4)*4 + reg.
    const bool lo = n0 < 2048;       // tile-uniform (n0 multiple of 256)
    __bf16* dst;
    int cb;
    size_t stride;
    if (MODE == 0) {
        dst = lo ? (__bf16*)out : (__bf16*)out2;
        cb = lo ? n0 : n0 - 2048;
        stride = 2048;
    } else {
        dst = (__bf16*)out;
        cb = n0;
        stride = (size_t)N;
    }
    float bvj[4];
#pragma unroll
    for (int nf = 0; nf < 4; ++nf) {
        const int gc = n0 + wn * 64 + nf * 16 + r;
        bvj[nf] = lo ? bias[gc] : bias2[gc - 2048];
    }

#pragma unroll
    for (int p = 0; p < 2; ++p) {
        if (wm == p) {
#pragma unroll
            for (int mm = 0; mm < 4; ++mm)
#pragma unroll
                for (int nf = 0; nf < 4; ++nf)
#pragma unroll
                    for (int k = 0; k < 4; ++k) {
                        const float v = acc[mm][nf][k] + bvj[nf];
                        const __bf16 o = (MODE == 0) ? (__bf16)(v * fsigmoid(v))
                                                     : (__bf16)v;
                        sm.ct[(mm * 16 + quad * 4 + k) * 264 +
                              (wn * 64 + nf * 16 + r)] = o;
                    }
        }
        __syncthreads();
#pragma unroll
        for (int q = 0; q < 4; ++q) {
            const int chunk = q * 512 + tid;      // 0..2047
            const int trow = chunk >> 5;          // 0..63
            const int tc = (chunk & 31) * 8;      // bf16 col, x8 chunk
            const bf16x8 vv = *(const bf16x8*)(sm.ct + trow * 264 + tc);
            // nt store: output not re-read soon; keep xb L3-resident.
            __builtin_nontemporal_store(vv,
                (bf16x8*)(dst + (size_t)(om0 + p * 64 + trow) * stride + cb + tc));
        }
        __syncthreads();
    }
}

// ---------------------------------------------------------------------------
// gemm3k (R20 loop, measured best): 256x256 tile, BK=64, 512 threads
// (8 waves, 2M x 4N, 128x64/wave), dual-buffered 128 KiB LDS. Per K-step:
// 4 quadrant phases, stagelets spread 1/phase, single late vmcnt(2) at
// phase 0 (never 0 in main loop). Recurrent GEMMs only (K=2048 -> T=32).
// MODE 4: bf16 out, dual bias. LDS chunk map: slot s -> row s>>3,
// stored-pos s&7 holds k-chunk (s&7)^(row&7).
// ---------------------------------------------------------------------------
template <int MODE>
__global__ __launch_bounds__(512, 2)
void gemm3k(const __bf16* __restrict__ A, const __bf16* __restrict__ Bt,
            const float* __restrict__ bias, const float* __restrict__ bias2,
            void* __restrict__ out, void* __restrict__ out2, int N, int K,
            int bps, int seg_stride, int row_off)
{
    struct KL { __bf16 A[256 * 64]; __bf16 B[256 * 64]; };   // 64 KiB
    __shared__ union SM3K {
        KL kl[2];                    // 128 KiB
        __bf16 ct[64 * 264];         // 33 KiB epilogue tile (64 x 256, pad 8)
    } sm;
    const int tid = threadIdx.x;                 // 0..511
    const int bx = blockIdx.x;
    const int seg = bx / bps;
    const int within = bx - seg * bps;
    const int gm0 = row_off + seg * seg_stride + within * 256;  // A row base
    const int om0 = bx * 256;                                   // out row base
    const int n0 = blockIdx.y * 256;

    // Staging: each 256x64 half = 2048 chunks; 4 per thread (s = tid + 512j).
    int rA[4], kA[4];
#pragma unroll
    for (int j = 0; j < 4; ++j) {
        const int s = tid + 512 * j;
        rA[j] = s >> 3;
        kA[j] = (s & 7) ^ (rA[j] & 7);
    }
    const __bf16* Agp[4];
    const __bf16* Bgp[4];
#pragma unroll
    for (int j = 0; j < 4; ++j) {
        Agp[j] = A  + (size_t)(gm0 + rA[j]) * K + kA[j] * 8;
        Bgp[j] = Bt + (size_t)(n0 + rA[j]) * K + kA[j] * 8;
    }

    const int lane = tid & 63;
    const int wave = tid >> 6;
    const int wm = wave >> 2;        // 0..1  (M half: 128 rows)
    const int wn = wave & 3;         // 0..3  (N quarter: 64 cols)
    const int quad = lane >> 4;
    const int r = lane & 15;

    f32x4 acc[8][4] = {};

    const int T = K >> 6;            // K-tiles of 64 (T=32 for K=2048)

    // Stagelets (2 loads each): SL0 = A rows 0-127; SL1 = A rows 128-255;
    // SL2 = B rows 0-127; SL3 = B rows 128-255.
    auto stagelet = [&](int t, int b, int p) {
        const int kt = t << 6;
        if (p == 0) {
            async_ld16(Agp[0] + kt, sm.kl[b].A + (tid      ) * 8);
            async_ld16(Agp[1] + kt, sm.kl[b].A + (tid + 512) * 8);
        } else if (p == 1) {
            async_ld16(Agp[2] + kt, sm.kl[b].A + (tid + 1024) * 8);
            async_ld16(Agp[3] + kt, sm.kl[b].A + (tid + 1536) * 8);
        } else if (p == 2) {
            async_ld16(Bgp[0] + kt, sm.kl[b].B + (tid      ) * 8);
            async_ld16(Bgp[1] + kt, sm.kl[b].B + (tid + 512) * 8);
        } else {
            async_ld16(Bgp[2] + kt, sm.kl[b].B + (tid + 1024) * 8);
            async_ld16(Bgp[3] + kt, sm.kl[b].B + (tid + 1536) * 8);
        }
    };

    // Prologue: all 4 stagelets of step 0 (8 loads outstanding).
#pragma unroll
    for (int p = 0; p < 4; ++p) stagelet(0, 0, p);

    const int swz0 = ((0 * 4 + quad) ^ (r & 7)) * 8;
    const int swz1 = ((1 * 4 + quad) ^ (r & 7)) * 8;

    for (int t = 0; t < T; ++t) {
        const int cur = t & 1;
        const bool pre = (t + 1) < T;
        const __bf16* apb = sm.kl[cur].A + (wm * 128 + r) * 64;
        const __bf16* bpb = sm.kl[cur].B + (wn * 64 + r) * 64;

        bf16x8 bfr[2][4];            // B frags [kslot][nf], live across phases

        // ---- phase 0: vmcnt+publish, read A m=0,1 + all B, 16 MFMA ----
        if (pre) {
            stagelet(t + 1, cur ^ 1, 0);
            // outstanding: SL0-3(t) [8] + SL0(t+1) [2] -> retire step t's 8.
            asm volatile("s_waitcnt vmcnt(2)" ::: "memory");
        } else {
            asm volatile("s_waitcnt vmcnt(0)" ::: "memory");
        }
        __builtin_amdgcn_s_barrier();            // publication of step t
        {
            bf16x8 a00 = *(const bf16x8*)(apb + 0 * 1024 + swz0);
            bf16x8 a01 = *(const bf16x8*)(apb + 0 * 1024 + swz1);
            bf16x8 a10 = *(const bf16x8*)(apb + 1 * 1024 + swz0);
            bf16x8 a11 = *(const bf16x8*)(apb + 1 * 1024 + swz1);
#pragma unroll
            for (int n = 0; n < 4; ++n) {
                bfr[0][n] = *(const bf16x8*)(bpb + n * 1024 + swz0);
                bfr[1][n] = *(const bf16x8*)(bpb + n * 1024 + swz1);
            }
            asm volatile("s_waitcnt lgkmcnt(0)" ::: "memory");
            __builtin_amdgcn_s_setprio(1);
#pragma unroll
            for (int n = 0; n < 4; ++n) {
                acc[0][n] = __builtin_amdgcn_mfma_f32_16x16x32_bf16(a00, bfr[0][n], acc[0][n], 0, 0, 0);
                acc[0][n] = __builtin_amdgcn_mfma_f32_16x16x32_bf16(a01, bfr[1][n], acc[0][n], 0, 0, 0);
                acc[1][n] = __builtin_amdgcn_mfma_f32_16x16x32_bf16(a10, bfr[0][n], acc[1][n], 0, 0, 0);
                acc[1][n] = __builtin_amdgcn_mfma_f32_16x16x32_bf16(a11, bfr[1][n], acc[1][n], 0, 0, 0);
            }
            __builtin_amdgcn_s_setprio(0);
        }
        __builtin_amdgcn_s_barrier();

        // ---- phases 1..3: read A m=2p,2p+1, stagelet p, 16 MFMA ----
#pragma unroll
        for (int p = 1; p < 4; ++p) {
            bf16x8 a00 = *(const bf16x8*)(apb + (2 * p    ) * 1024 + swz0);
            bf16x8 a01 = *(const bf16x8*)(apb + (2 * p    ) * 1024 + swz1);
            bf16x8 a10 = *(const bf16x8*)(apb + (2 * p + 1) * 1024 + swz0);
            bf16x8 a11 = *(const bf16x8*)(apb + (2 * p + 1) * 1024 + swz1);
            if (pre) stagelet(t + 1, cur ^ 1, p);
            __builtin_amdgcn_s_barrier();        // (a) scheduling
            asm volatile("s_waitcnt lgkmcnt(0)" ::: "memory");
            __builtin_amdgcn_s_setprio(1);
#pragma unroll
            for (int n = 0; n < 4; ++n) {
                acc[2 * p][n]     = __builtin_amdgcn_mfma_f32_16x16x32_bf16(a00, bfr[0][n], acc[2 * p][n], 0, 0, 0);
                acc[2 * p][n]     = __builtin_amdgcn_mfma_f32_16x16x32_bf16(a01, bfr[1][n], acc[2 * p][n], 0, 0, 0);
                acc[2 * p + 1][n] = __builtin_amdgcn_mfma_f32_16x16x32_bf16(a10, bfr[0][n], acc[2 * p + 1][n], 0, 0, 0);
                acc[2 * p + 1][n] = __builtin_amdgcn_mfma_f32_16x16x32_bf16(a11, bfr[1][n], acc[2 * p + 1][n], 0, 0, 0);
            }
            __builtin_amdgcn_s_setprio(0);
            __builtin_amdgcn_s_barrier();        // (b)
        }
    }

    // Epilogue. C/D layout (m89). 4 passes of 64 rows through ct (stride 264).
    __syncthreads();

    const bool lo = n0 < 2048;       // tile-uniform (n0 multiple of 256)
    __bf16* dst = (__bf16*)out;
    const int cb = n0;
    const size_t stride = (size_t)N;
    float bvj[4];
#pragma unroll
    for (int nf = 0; nf < 4; ++nf) {
        const int gc = n0 + wn * 64 + nf * 16 + r;
        bvj[nf] = lo ? bias[gc] : bias2[gc - 2048];
    }

#pragma unroll
    for (int p = 0; p < 4; ++p) {
        if (wm == (p >> 1)) {
            const int mb = (p & 1) * 4;
#pragma unroll
            for (int mm = 0; mm < 4; ++mm)
#pragma unroll
                for (int nf = 0; nf < 4; ++nf)
#pragma unroll
                    for (int k = 0; k < 4; ++k) {
                        const float v = acc[mb + mm][nf][k] + bvj[nf];
                        sm.ct[(mm * 16 + quad * 4 + k) * 264 +
                              (wn * 64 + nf * 16 + r)] = (__bf16)v;
                    }
        }
        __syncthreads();
#pragma unroll
        for (int q = 0; q < 4; ++q) {
            const int chunk = q * 512 + tid;      // 0..2047
            const int trow = chunk >> 5;          // 0..63
            const int tc = (chunk & 31) * 8;      // bf16 col, x8 chunk
            const bf16x8 vv = *(const bf16x8*)(sm.ct + trow * 264 + tc);
            // nt store: rawzh read only by the later scan; keep xin resident.
            __builtin_nontemporal_store(vv,
                (bf16x8*)(dst + (size_t)(om0 + p * 64 + trow) * stride + cb + tc));
        }
        __syncthreads();
    }
}

// ---------------------------------------------------------------------------
// gemm_bt64: 128x128 tile, BK=64, 256 threads (4 waves, 64x64/wave), dual
// 64 KiB LDS, counted vmcnt(8). Output GEMM (K=2048, T=32). MODE 3: fp32.
// ---------------------------------------------------------------------------
template <int MODE>
__global__ __launch_bounds__(256)
void gemm_bt64(const __bf16* __restrict__ A, const __bf16* __restrict__ Bt,
               const float* __restrict__ bias, const float* __restrict__ bias2,
               void* __restrict__ out, void* __restrict__ out2, int N, int K,
               int bps, int seg_stride, int row_off)
{
    struct KL64 { __bf16 A[128 * 64]; __bf16 B[128 * 64]; };   // 32 KiB
    __shared__ union SMB64 {
        KL64 kl[2];                  // 64 KiB
        float  ctf[32 * 132];        // 17 KiB fp32 epilogue tile
    } sm;
    const int tid = threadIdx.x;                 // 0..255
    const int bx = blockIdx.x;
    const int seg = bx / bps;
    const int within = bx - seg * bps;
    const int gm0 = row_off + seg * seg_stride + within * 128;  // A row base
    const int om0 = bx * 128;                                   // out row base
    const int n0 = blockIdx.y * 128;

    int rS[4], kS[4];
#pragma unroll
    for (int j = 0; j < 4; ++j) {
        const int s = tid + 256 * j;
        rS[j] = s >> 3;
        kS[j] = (s & 7) ^ (rS[j] & 7);
    }
    const __bf16* Agp[4];
    const __bf16* Bgp[4];
#pragma unroll
    for (int j = 0; j < 4; ++j) {
        Agp[j] = A  + (size_t)(gm0 + rS[j]) * K + kS[j] * 8;
        Bgp[j] = Bt + (size_t)(n0 + rS[j]) * K + kS[j] * 8;
    }

    const int lane = tid & 63;
    const int wave = tid >> 6;
    const int wrow = (wave >> 1) * 64;
    const int wcol = (wave & 1) * 64;
    const int quad = lane >> 4;
    const int r = lane & 15;

    f32x4 acc[4][4] = {};

    const int T = K >> 6;            // K-tiles of 64 (T=32 for K=2048)

    auto stage = [&](int t, int b) {
        const int kt = t << 6;
#pragma unroll
        for (int j = 0; j < 4; ++j)
            async_ld16(Agp[j] + kt, sm.kl[b].A + (tid + 256 * j) * 8);
#pragma unroll
        for (int j = 0; j < 4; ++j)
            async_ld16(Bgp[j] + kt, sm.kl[b].B + (tid + 256 * j) * 8);
    };

    stage(0, 0);                     // 8 outstanding

    const int swz0 = ((0 * 4 + quad) ^ (r & 7)) * 8;
    const int swz1 = ((1 * 4 + quad) ^ (r & 7)) * 8;

    for (int t = 0; t < T; ++t) {
        const int cur = t & 1;
        if (t + 1 < T) {
            stage(t + 1, cur ^ 1);   // 16 outstanding
            asm volatile("s_waitcnt vmcnt(8)\n\ts_barrier" ::: "memory");
        } else {
            asm volatile("s_waitcnt vmcnt(0)\n\ts_barrier" ::: "memory");
        }

        const __bf16* apb = sm.kl[cur].A + (wrow + r) * 64;
        const __bf16* bpb = sm.kl[cur].B + (wcol + r) * 64;

#pragma unroll
        for (int ks = 0; ks < 2; ++ks) {
            const int swz = ks ? swz1 : swz0;
            bf16x8 af[4], bf_[4];
#pragma unroll
            for (int m = 0; m < 4; ++m)
                af[m] = *(const bf16x8*)(apb + m * 1024 + swz);
#pragma unroll
            for (int n = 0; n < 4; ++n)
                bf_[n] = *(const bf16x8*)(bpb + n * 1024 + swz);

            __builtin_amdgcn_s_setprio(1);
#pragma unroll
            for (int m = 0; m < 4; ++m)
#pragma unroll
                for (int n = 0; n < 4; ++n)
                    acc[m][n] = __builtin_amdgcn_mfma_f32_16x16x32_bf16(
                        af[m], bf_[n], acc[m][n], 0, 0, 0);
            __builtin_amdgcn_s_setprio(0);
        }

        asm volatile("s_waitcnt lgkmcnt(0)\n\ts_barrier" ::: "memory");
    }

    // fp32 staged epilogue: 4 passes of 32 rows through [32][132] LDS.
    {
        float bvj[4];
#pragma unroll
        for (int j = 0; j < 4; ++j)
            bvj[j] = bias[n0 + wcol + j * 16 + r];
#pragma unroll
        for (int p = 0; p < 4; ++p) {
#pragma unroll
            for (int j = 0; j < 4; ++j)
#pragma unroll
                for (int k = 0; k < 4; ++k)
                    sm.ctf[((wave >> 1) * 16 + quad * 4 + k) * 132 +
                           (wcol + j * 16 + r)] = acc[p][j][k] + bvj[j];
            __syncthreads();
#pragma unroll
            for (int q = 0; q < 4; ++q) {
                const int chunk = q * 256 + tid;      // 0..1023
                const int trow = chunk >> 5;          // 0..31
                const int tc4 = (chunk & 31) * 4;     // fp32 col, x4 chunk
                const f32x4 vv = *(const f32x4*)(sm.ctf + trow * 132 + tc4);
                const int grow = om0 + (trow >> 4) * 64 + p * 16 + (trow & 15);
                // nt store: d_out never re-read by the GPU.
                __builtin_nontemporal_store(vv,
                    (f32x4*)((float*)out + (size_t)grow * N + n0 + tc4));
            }
            __syncthreads();
        }
    }
}

// Parallel minGRU scan over one chunk, on raw pre-activations:
// z = sigmoid(raw_z), b = z * raw_h, h = (1-z)h + b.
// raw is [B*CS][4096] (z cols 0..2047, h cols 2048..4095).
#define SSEG 32
#define SCOLS 32
__global__ __launch_bounds__(1024)
void scan_kernel(const __bf16* __restrict__ raw, __bf16* __restrict__ xskip,
                 float* __restrict__ carry, int CS, int S, int t0, int first)
{
    __shared__ float Als[SSEG][SCOLS];
    __shared__ float Bls[SSEG][SCOLS];
    const int lane = threadIdx.x & (SCOLS - 1);   // col within group
    const int w = threadIdx.x >> 5;               // segment 0..31
    const int nb8 = gridDim.x >> 3;
    const int lin = (blockIdx.x & 7) * nb8 + (blockIdx.x >> 3);
    const int gpb = 2048 / SCOLS;                 // 64 groups per batch
    const int batch = lin / gpb;
    const int col = (lin - batch * gpb) * SCOLS + lane;
    const int L = CS / SSEG;                      // 32 (CS always 1024)
    const int tbeg = w * L;

    const size_t rbase = ((size_t)batch * CS + tbeg) * 4096 + col;

    float av[32], bv[32];
    float A = 1.0f, Bv = 0.0f;
    {
        size_t idx = rbase;
#pragma unroll
        for (int t = 0; t < 32; ++t, idx += 4096) {
            const float z = fsigmoid((float)raw[idx]);
            const float b = z * (float)raw[idx + 2048];
            const float a = 1.0f - z;
            av[t] = a;
            bv[t] = b;
            Bv = a * Bv + b;
            A *= a;
        }
    }
    Als[w][lane] = A;
    Bls[w][lane] = Bv;
    __syncthreads();

    const int ch = batch * 2048 + col;
    float h = first ? 0.0f : carry[ch];
    for (int s = 0; s < w; ++s)
        h = Als[s][lane] * h + Bls[s][lane];
    if (w == SSEG - 1)
        carry[ch] = A * h + Bv;

    {
        size_t gidx = ((size_t)batch * S + t0 + tbeg) * 2048 + col;
#pragma unroll
        for (int t = 0; t < 32; ++t, gidx += 2048) {
            h = av[t] * h + bv[t];
            xskip[gidx] = (__bf16)((float)xskip[gidx] + h);
        }
    }
}

// ---------------------------------------------------------------------------
// prep_kernel: fused prepass. Block-range dispatch (branch is block-uniform):
//   [0, 8192)            conv x fp32 -> xb bf16 (float4 granularity)
//   [8192, 8192+2048)    Wt12: transpose W_in1/W_in2 (K=512,  N=2048), z=hi
//   [+2048, +2048+8192)  Wtzh: transpose W_z/W_h    (K=2048, N=2048), z=hi
//   [.., +1024)          Wto:  transpose W_out      (K=2048, N=512)
// ---------------------------------------------------------------------------
__global__ __launch_bounds__(256)
void prep_kernel(const float* __restrict__ x, __bf16* __restrict__ xb,
                 const float* __restrict__ W_in1, const float* __restrict__ W_in2,
                 __bf16* __restrict__ Wt12,
                 const float* __restrict__ W_z, const float* __restrict__ W_h,
                 __bf16* __restrict__ Wtzh,
                 const float* __restrict__ W_out, __bf16* __restrict__ Wto)
{
    __shared__ float tile[32][33];
    int bid = blockIdx.x;
    if (bid < 8192) {                      // conv: 8192*256 float4 = M*H
        const int i = bid * 256 + threadIdx.x;
        const float4 v = ((const float4*)x)[i];
        bf16x4 o;
        o[0] = (__bf16)v.x; o[1] = (__bf16)v.y;
        o[2] = (__bf16)v.z; o[3] = (__bf16)v.w;
        ((bf16x4*)xb)[i] = o;
        return;
    }
    bid -= 8192;
    const float* W;
    __bf16* dst;
    int K, N, nb, kb;
    if (bid < 2048) {                      // Wt12 (K=512, N=2048)
        const int z = bid >> 10, rem = bid & 1023;
        W = z ? W_in2 : W_in1;
        dst = Wt12 + (size_t)z * 512 * 2048;
        K = 512; N = 2048;
        nb = (rem & 63) * 32; kb = (rem >> 6) * 32;   // rem = kb*64 + nb
    } else if (bid < 2048 + 8192) {        // Wtzh (K=2048, N=2048)
        const int b2 = bid - 2048;
        const int z = b2 >> 12, rem = b2 & 4095;
        W = z ? W_h : W_z;
        dst = Wtzh + (size_t)z * 2048 * 2048;
        K = 2048; N = 2048;
        nb = (rem & 63) * 32; kb = (rem >> 6) * 32;
    } else {                               // Wto (K=2048, N=512)
        const int b3 = bid - (2048 + 8192);
        W = W_out; dst = Wto;
        K = 2048; N = 512;
        nb = (b3 & 15) * 32; kb = (b3 >> 4) * 32;
    }
    const int tx = threadIdx.x & 31;
    const int ty = threadIdx.x >> 5;
#pragma unroll
    for (int i = 0; i < 32; i += 8)
        tile[ty + i][tx] = W[(size_t)(kb + ty + i) * N + nb + tx];
    __syncthreads();
#pragma unroll
    for (int i = 0; i < 32; i += 8)
        dst[(size_t)(nb + ty + i) * K + kb + tx] = (__bf16)tile[tx][ty + i];
}

extern "C" void kernel_launch(void* const* d_in, const int* in_sizes, int n_in,
                              void* d_out, int out_size, void* d_ws, size_t ws_size,
                              hipStream_t stream)
{
    const float* x     = (const float*)d_in[0];
    const float* W_in1 = (const float*)d_in[1];
    const float* b_in1 = (const float*)d_in[2];
    const float* W_in2 = (const float*)d_in[3];
    const float* b_in2 = (const float*)d_in[4];
    const float* W_z   = (const float*)d_in[5];
    const float* b_z   = (const float*)d_in[6];
    const float* W_h   = (const float*)d_in[7];
    const float* b_h   = (const float*)d_in[8];
    const float* W_out = (const float*)d_in[9];
    const float* b_out = (const float*)d_in[10];

    const int B = 4, S = 4096, H = 512, E = 2048;
    const int M = B * S;        // 16384
    const int CS = 1024;        // chunk length
    const int NC = S / CS;      // 4 chunks
    const int MC = B * CS;      // 4096 rows per chunk

    const size_t MiB = 1024 * 1024;
    const size_t NEEDED = 183 * MiB;
    if (ws_size < NEEDED) return;

    char* ws = (char*)d_ws;
    __bf16* xb    = (__bf16*)(ws + 0);        // overlaid by rawzh after use
    __bf16* rawzh = (__bf16*)(ws + 0);
    float*  carry = (float*) (ws + 32 * MiB);
    __bf16* xin   = (__bf16*)(ws + 33 * MiB);
    __bf16* xskip = (__bf16*)(ws + 97 * MiB);
    __bf16* Wt12  = (__bf16*)(ws + 161 * MiB);
    __bf16* Wtzh  = (__bf16*)(ws + 165 * MiB);
    __bf16* Wto   = (__bf16*)(ws + 181 * MiB);

    // Fused prepass: conv + all 5 weight transposes in one launch.
    prep_kernel<<<8192 + 2048 + 8192 + 1024, 256, 0, stream>>>(
        x, xb, W_in1, W_in2, Wt12, W_z, W_h, Wtzh, W_out, Wto);

    // Merged input GEMM: N=4096 (W1|W2), split-silu epilogue -> xin / xskip
    // gemm4 128x256 tiles, BK=32, 3 blk/CU: grid 128 x 16.
    gemm4<0><<<dim3(M / 128, 2 * E / 256), 512, 0, stream>>>(
        xb, Wt12, b_in1, b_in2, xin, xskip, 2 * E, H, M / 128, 0, 0);

    // Recurrent stage, chunked over S (rawzh overlays dead xb)
    // gemm3k (R20 4-phase + spread stagelets) 256^2, BK=64: grid 16x16, T=32.
    for (int c = 0; c < NC; ++c) {
        const int row_off = c * CS;
        gemm3k<4><<<dim3(MC / 256, 2 * E / 256), 512, 0, stream>>>(
            xin, Wtzh, b_z, b_h, rawzh, nullptr, 2 * E, E, CS / 256, S, row_off);
        scan_kernel<<<(B * E) / SCOLS, 1024, 0, stream>>>(
            rawzh, xskip, carry, CS, S, row_off, c == 0);
    }

    // Output GEMM (full M), fp32 out -- BK=64 (K=2048, T=32), grid 512 = 2/CU.
    gemm_bt64<3><<<dim3(M / 128, H / 128), 256, 0, stream>>>(
        xskip, Wto, b_out, nullptr, (float*)d_out, nullptr, H, E, M / 128, 0, 0);
}

// Round 15
// 565.371 us; speedup vs baseline: 1.0605x; 1.0224x over previous
//
#include <hip/hip_runtime.h>
#include <hip/hip_bf16.h>

// Gramba (fp32 in / fp32 out): x_in = silu(x@W1+b1); x_skip = silu(x@W2+b2)
//         z = sigmoid(x_in@Wz+bz); h~ = x_in@Wh+bh
//         h = scan(h = (1-z)h + z*h~); out = (x_skip+h)@Wo + bo
// R23 == R20 byte-exact (measured best, 567.9 us). R22's nontemporal stores
// reverted: FETCH dropped 61->50 MB as predicted but the nt write path cost
// more than the fetch saving (gemm4 105->109.5; total +10). Ledger of sync
// experiments on gemm3k: R20 {4-phase + spread stagelets + vmcnt(2)} is the
// only winner; R13 (8-barrier), R21 (bulk+phases), R22 (nt) all regressed.
//   gemm4<0> input (128x256 BK=32, 3 blk/CU), gemm3k<4> recurrent (256^2
//   BK=64, 4-phase), gemm_bt64<3> output (BK=64), R9 scan, fused prep.
//
// Workspace layout (183 MiB):
//   [0,32)    rawzh chunk (bf16, 4096x4096)   [xb overlays [0,16) before use]
//   [32,33)   carry (fp32 h state, 4x2048)
//   [33,97)   xin   (bf16, 16384x2048)
//   [97,161)  xskip (bf16; scan overwrites with s = x_skip+h)
//   [161,165) Wt12  (bf16 [4096][512])
//   [165,181) Wtzh  (bf16 [4096][2048])
//   [181,183) Wto   (bf16 [512][2048])

typedef __bf16 bf16x8 __attribute__((ext_vector_type(8)));
typedef __bf16 bf16x4 __attribute__((ext_vector_type(4)));
typedef float  f32x4  __attribute__((ext_vector_type(4)));

#define DEVINL __device__ __forceinline__

DEVINL void async_ld16(const __bf16* g, __bf16* l) {
    __builtin_amdgcn_global_load_lds(
        (const __attribute__((address_space(1))) void*)g,
        (__attribute__((address_space(3))) void*)l, 16, 0, 0);
}

DEVINL float fsigmoid(float v) { return 1.0f / (1.0f + __expf(-v)); }

// ---------------------------------------------------------------------------
// gemm4: 128x256 tile, 512 threads (8 waves, 2M x 4N, 64x64/wave), BK=32,
// dual-buffered 48 KiB LDS (3 blk/CU), depth-1 counted-vmcnt(3) schedule.
// Input GEMM (K=512). MODE 0: dual split-silu -> bf16 out/out2.
// ---------------------------------------------------------------------------
template <int MODE>
__global__ __launch_bounds__(512, 4)
void gemm4(const __bf16* __restrict__ A, const __bf16* __restrict__ Bt,
           const float* __restrict__ bias, const float* __restrict__ bias2,
           void* __restrict__ out, void* __restrict__ out2, int N, int K,
           int bps, int seg_stride, int row_off)
{
    struct KL { __bf16 A[128 * 32]; __bf16 B[256 * 32]; };   // 24 KiB
    __shared__ union SM4 {
        KL kl[2];                    // 48 KiB
        __bf16 ct[64 * 264];         // 33 KiB epilogue tile (64 x 256, pad 8)
    } sm;
    const int tid = threadIdx.x;                 // 0..511
    const int bx = blockIdx.x;
    const int seg = bx / bps;
    const int within = bx - seg * bps;
    const int gm0 = row_off + seg * seg_stride + within * 128;  // A row base
    const int om0 = bx * 128;                                   // out row base
    const int n0 = blockIdx.y * 256;

    const int rA = tid >> 2,         kA = (tid & 3) ^ ((tid >> 3) & 3);
    const int c0 = tid, c1 = tid + 512;
    const int rB0 = c0 >> 2,         kB0 = (c0 & 3) ^ ((c0 >> 3) & 3);
    const int rB1 = c1 >> 2,         kB1 = (c1 & 3) ^ ((c1 >> 3) & 3);
    const __bf16* Ag  = A  + (size_t)(gm0 + rA)  * K + kA  * 8;
    const __bf16* Bg0 = Bt + (size_t)(n0 + rB0) * K + kB0 * 8;
    const __bf16* Bg1 = Bt + (size_t)(n0 + rB1) * K + kB1 * 8;

    const int lane = tid & 63;
    const int wave = tid >> 6;
    const int wm = wave >> 2;        // 0..1  (M half: 64 rows)
    const int wn = wave & 3;         // 0..3  (N quarter: 64 cols)
    const int quad = lane >> 4;
    const int r = lane & 15;
    const int swz = (quad ^ ((r >> 1) & 3)) * 8;

    f32x4 acc[4][4] = {};

    const int T = K >> 5;            // K-tiles of 32 (T=16 for K=512)

    auto stage = [&](int t, int b) {
        const int kt = t << 5;
        async_ld16(Ag  + kt, sm.kl[b].A + tid * 8);
        async_ld16(Bg0 + kt, sm.kl[b].B + c0 * 8);
        async_ld16(Bg1 + kt, sm.kl[b].B + c1 * 8);
    };

    stage(0, 0);

    for (int t = 0; t < T; ++t) {
        const int cur = t & 1;
        if (t + 1 < T) {
            stage(t + 1, cur ^ 1);   // 3 loads -> 6 outstanding
            asm volatile("s_waitcnt vmcnt(3)\n\ts_barrier" ::: "memory");
        } else {
            asm volatile("s_waitcnt vmcnt(0)\n\ts_barrier" ::: "memory");
        }

        const __bf16* ap = sm.kl[cur].A + (wm * 64 + r) * 32 + swz;
        const __bf16* bp = sm.kl[cur].B + (wn * 64 + r) * 32 + swz;
        bf16x8 af[4], bf_[4];
#pragma unroll
        for (int m = 0; m < 4; ++m) af[m] = *(const bf16x8*)(ap + m * 512);
#pragma unroll
        for (int n = 0; n < 4; ++n) bf_[n] = *(const bf16x8*)(bp + n * 512);

        __builtin_amdgcn_s_setprio(1);
#pragma unroll
        for (int m = 0; m < 4; ++m)
#pragma unroll
            for (int n = 0; n < 4; ++n)
                acc[m][n] = __builtin_amdgcn_mfma_f32_16x16x32_bf16(
                    af[m], bf_[n], acc[m][n], 0, 0, 0);
        __builtin_amdgcn_s_setprio(0);

        asm volatile("s_waitcnt lgkmcnt(0)\n\ts_barrier" ::: "memory");
    }

    // Epilogue. C/D layout (m89): col = lane&15, row = (lane>>4)*4 + reg.
    const bool lo = n0 < 2048;       // tile-uniform (n0 multiple of 256)
    __bf16* dst;
    int cb;
    size_t stride;
    if (MODE == 0) {
        dst = lo ? (__bf16*)out : (__bf16*)out2;
        cb = lo ? n0 : n0 - 2048;
        stride = 2048;
    } else {
        dst = (__bf16*)out;
        cb = n0;
        stride = (size_t)N;
    }
    float bvj[4];
#pragma unroll
    for (int nf = 0; nf < 4; ++nf) {
        const int gc = n0 + wn * 64 + nf * 16 + r;
        bvj[nf] = lo ? bias[gc] : bias2[gc - 2048];
    }

#pragma unroll
    for (int p = 0; p < 2; ++p) {
        if (wm == p) {
#pragma unroll
            for (int mm = 0; mm < 4; ++mm)
#pragma unroll
                for (int nf = 0; nf < 4; ++nf)
#pragma unroll
                    for (int k = 0; k < 4; ++k) {
                        const float v = acc[mm][nf][k] + bvj[nf];
                        const __bf16 o = (MODE == 0) ? (__bf16)(v * fsigmoid(v))
                                                     : (__bf16)v;
                        sm.ct[(mm * 16 + quad * 4 + k) * 264 +
                              (wn * 64 + nf * 16 + r)] = o;
                    }
        }
        __syncthreads();
#pragma unroll
        for (int q = 0; q < 4; ++q) {
            const int chunk = q * 512 + tid;      // 0..2047
            const int trow = chunk >> 5;          // 0..63
            const int tc = (chunk & 31) * 8;      // bf16 col, x8 chunk
            const bf16x8 vv = *(const bf16x8*)(sm.ct + trow * 264 + tc);
            *(bf16x8*)(dst + (size_t)(om0 + p * 64 + trow) * stride + cb + tc) = vv;
        }
        __syncthreads();
    }
}

// ---------------------------------------------------------------------------
// gemm3k (R20 loop, measured best): 256x256 tile, BK=64, 512 threads
// (8 waves, 2M x 4N, 128x64/wave), dual-buffered 128 KiB LDS. Per K-step:
// 4 quadrant phases, stagelets spread 1/phase, single late vmcnt(2) at
// phase 0 (never 0 in main loop). Recurrent GEMMs only (K=2048 -> T=32).
// MODE 4: bf16 out, dual bias. LDS chunk map: slot s -> row s>>3,
// stored-pos s&7 holds k-chunk (s&7)^(row&7).
// ---------------------------------------------------------------------------
template <int MODE>
__global__ __launch_bounds__(512, 2)
void gemm3k(const __bf16* __restrict__ A, const __bf16* __restrict__ Bt,
            const float* __restrict__ bias, const float* __restrict__ bias2,
            void* __restrict__ out, void* __restrict__ out2, int N, int K,
            int bps, int seg_stride, int row_off)
{
    struct KL { __bf16 A[256 * 64]; __bf16 B[256 * 64]; };   // 64 KiB
    __shared__ union SM3K {
        KL kl[2];                    // 128 KiB
        __bf16 ct[64 * 264];         // 33 KiB epilogue tile (64 x 256, pad 8)
    } sm;
    const int tid = threadIdx.x;                 // 0..511
    const int bx = blockIdx.x;
    const int seg = bx / bps;
    const int within = bx - seg * bps;
    const int gm0 = row_off + seg * seg_stride + within * 256;  // A row base
    const int om0 = bx * 256;                                   // out row base
    const int n0 = blockIdx.y * 256;

    // Staging: each 256x64 half = 2048 chunks; 4 per thread (s = tid + 512j).
    int rA[4], kA[4];
#pragma unroll
    for (int j = 0; j < 4; ++j) {
        const int s = tid + 512 * j;
        rA[j] = s >> 3;
        kA[j] = (s & 7) ^ (rA[j] & 7);
    }
    const __bf16* Agp[4];
    const __bf16* Bgp[4];
#pragma unroll
    for (int j = 0; j < 4; ++j) {
        Agp[j] = A  + (size_t)(gm0 + rA[j]) * K + kA[j] * 8;
        Bgp[j] = Bt + (size_t)(n0 + rA[j]) * K + kA[j] * 8;
    }

    const int lane = tid & 63;
    const int wave = tid >> 6;
    const int wm = wave >> 2;        // 0..1  (M half: 128 rows)
    const int wn = wave & 3;         // 0..3  (N quarter: 64 cols)
    const int quad = lane >> 4;
    const int r = lane & 15;

    f32x4 acc[8][4] = {};

    const int T = K >> 6;            // K-tiles of 64 (T=32 for K=2048)

    // Stagelets (2 loads each): SL0 = A rows 0-127; SL1 = A rows 128-255;
    // SL2 = B rows 0-127; SL3 = B rows 128-255.
    auto stagelet = [&](int t, int b, int p) {
        const int kt = t << 6;
        if (p == 0) {
            async_ld16(Agp[0] + kt, sm.kl[b].A + (tid      ) * 8);
            async_ld16(Agp[1] + kt, sm.kl[b].A + (tid + 512) * 8);
        } else if (p == 1) {
            async_ld16(Agp[2] + kt, sm.kl[b].A + (tid + 1024) * 8);
            async_ld16(Agp[3] + kt, sm.kl[b].A + (tid + 1536) * 8);
        } else if (p == 2) {
            async_ld16(Bgp[0] + kt, sm.kl[b].B + (tid      ) * 8);
            async_ld16(Bgp[1] + kt, sm.kl[b].B + (tid + 512) * 8);
        } else {
            async_ld16(Bgp[2] + kt, sm.kl[b].B + (tid + 1024) * 8);
            async_ld16(Bgp[3] + kt, sm.kl[b].B + (tid + 1536) * 8);
        }
    };

    // Prologue: all 4 stagelets of step 0 (8 loads outstanding).
#pragma unroll
    for (int p = 0; p < 4; ++p) stagelet(0, 0, p);

    const int swz0 = ((0 * 4 + quad) ^ (r & 7)) * 8;
    const int swz1 = ((1 * 4 + quad) ^ (r & 7)) * 8;

    for (int t = 0; t < T; ++t) {
        const int cur = t & 1;
        const bool pre = (t + 1) < T;
        const __bf16* apb = sm.kl[cur].A + (wm * 128 + r) * 64;
        const __bf16* bpb = sm.kl[cur].B + (wn * 64 + r) * 64;

        bf16x8 bfr[2][4];            // B frags [kslot][nf], live across phases

        // ---- phase 0: vmcnt+publish, read A m=0,1 + all B, 16 MFMA ----
        if (pre) {
            stagelet(t + 1, cur ^ 1, 0);
            // outstanding: SL0-3(t) [8] + SL0(t+1) [2] -> retire step t's 8.
            asm volatile("s_waitcnt vmcnt(2)" ::: "memory");
        } else {
            asm volatile("s_waitcnt vmcnt(0)" ::: "memory");
        }
        __builtin_amdgcn_s_barrier();            // publication of step t
        {
            bf16x8 a00 = *(const bf16x8*)(apb + 0 * 1024 + swz0);
            bf16x8 a01 = *(const bf16x8*)(apb + 0 * 1024 + swz1);
            bf16x8 a10 = *(const bf16x8*)(apb + 1 * 1024 + swz0);
            bf16x8 a11 = *(const bf16x8*)(apb + 1 * 1024 + swz1);
#pragma unroll
            for (int n = 0; n < 4; ++n) {
                bfr[0][n] = *(const bf16x8*)(bpb + n * 1024 + swz0);
                bfr[1][n] = *(const bf16x8*)(bpb + n * 1024 + swz1);
            }
            asm volatile("s_waitcnt lgkmcnt(0)" ::: "memory");
            __builtin_amdgcn_s_setprio(1);
#pragma unroll
            for (int n = 0; n < 4; ++n) {
                acc[0][n] = __builtin_amdgcn_mfma_f32_16x16x32_bf16(a00, bfr[0][n], acc[0][n], 0, 0, 0);
                acc[0][n] = __builtin_amdgcn_mfma_f32_16x16x32_bf16(a01, bfr[1][n], acc[0][n], 0, 0, 0);
                acc[1][n] = __builtin_amdgcn_mfma_f32_16x16x32_bf16(a10, bfr[0][n], acc[1][n], 0, 0, 0);
                acc[1][n] = __builtin_amdgcn_mfma_f32_16x16x32_bf16(a11, bfr[1][n], acc[1][n], 0, 0, 0);
            }
            __builtin_amdgcn_s_setprio(0);
        }
        __builtin_amdgcn_s_barrier();

        // ---- phases 1..3: read A m=2p,2p+1, stagelet p, 16 MFMA ----
#pragma unroll
        for (int p = 1; p < 4; ++p) {
            bf16x8 a00 = *(const bf16x8*)(apb + (2 * p    ) * 1024 + swz0);
            bf16x8 a01 = *(const bf16x8*)(apb + (2 * p    ) * 1024 + swz1);
            bf16x8 a10 = *(const bf16x8*)(apb + (2 * p + 1) * 1024 + swz0);
            bf16x8 a11 = *(const bf16x8*)(apb + (2 * p + 1) * 1024 + swz1);
            if (pre) stagelet(t + 1, cur ^ 1, p);
            __builtin_amdgcn_s_barrier();        // (a) scheduling
            asm volatile("s_waitcnt lgkmcnt(0)" ::: "memory");
            __builtin_amdgcn_s_setprio(1);
#pragma unroll
            for (int n = 0; n < 4; ++n) {
                acc[2 * p][n]     = __builtin_amdgcn_mfma_f32_16x16x32_bf16(a00, bfr[0][n], acc[2 * p][n], 0, 0, 0);
                acc[2 * p][n]     = __builtin_amdgcn_mfma_f32_16x16x32_bf16(a01, bfr[1][n], acc[2 * p][n], 0, 0, 0);
                acc[2 * p + 1][n] = __builtin_amdgcn_mfma_f32_16x16x32_bf16(a10, bfr[0][n], acc[2 * p + 1][n], 0, 0, 0);
                acc[2 * p + 1][n] = __builtin_amdgcn_mfma_f32_16x16x32_bf16(a11, bfr[1][n], acc[2 * p + 1][n], 0, 0, 0);
            }
            __builtin_amdgcn_s_setprio(0);
            __builtin_amdgcn_s_barrier();        // (b)
        }
    }

    // Epilogue. C/D layout (m89). 4 passes of 64 rows through ct (stride 264).
    __syncthreads();

    const bool lo = n0 < 2048;       // tile-uniform (n0 multiple of 256)
    __bf16* dst = (__bf16*)out;
    const int cb = n0;
    const size_t stride = (size_t)N;
    float bvj[4];
#pragma unroll
    for (int nf = 0; nf < 4; ++nf) {
        const int gc = n0 + wn * 64 + nf * 16 + r;
        bvj[nf] = lo ? bias[gc] : bias2[gc - 2048];
    }

#pragma unroll
    for (int p = 0; p < 4; ++p) {
        if (wm == (p >> 1)) {
            const int mb = (p & 1) * 4;
#pragma unroll
            for (int mm = 0; mm < 4; ++mm)
#pragma unroll
                for (int nf = 0; nf < 4; ++nf)
#pragma unroll
                    for (int k = 0; k < 4; ++k) {
                        const float v = acc[mb + mm][nf][k] + bvj[nf];
                        sm.ct[(mm * 16 + quad * 4 + k) * 264 +
                              (wn * 64 + nf * 16 + r)] = (__bf16)v;
                    }
        }
        __syncthreads();
#pragma unroll
        for (int q = 0; q < 4; ++q) {
            const int chunk = q * 512 + tid;      // 0..2047
            const int trow = chunk >> 5;          // 0..63
            const int tc = (chunk & 31) * 8;      // bf16 col, x8 chunk
            const bf16x8 vv = *(const bf16x8*)(sm.ct + trow * 264 + tc);
            *(bf16x8*)(dst + (size_t)(om0 + p * 64 + trow) * stride + cb + tc) = vv;
        }
        __syncthreads();
    }
}

// ---------------------------------------------------------------------------
// gemm_bt64: 128x128 tile, BK=64, 256 threads (4 waves, 64x64/wave), dual
// 64 KiB LDS, counted vmcnt(8). Output GEMM (K=2048, T=32). MODE 3: fp32.
// ---------------------------------------------------------------------------
template <int MODE>
__global__ __launch_bounds__(256)
void gemm_bt64(const __bf16* __restrict__ A, const __bf16* __restrict__ Bt,
               const float* __restrict__ bias, const float* __restrict__ bias2,
               void* __restrict__ out, void* __restrict__ out2, int N, int K,
               int bps, int seg_stride, int row_off)
{
    struct KL64 { __bf16 A[128 * 64]; __bf16 B[128 * 64]; };   // 32 KiB
    __shared__ union SMB64 {
        KL64 kl[2];                  // 64 KiB
        float  ctf[32 * 132];        // 17 KiB fp32 epilogue tile
    } sm;
    const int tid = threadIdx.x;                 // 0..255
    const int bx = blockIdx.x;
    const int seg = bx / bps;
    const int within = bx - seg * bps;
    const int gm0 = row_off + seg * seg_stride + within * 128;  // A row base
    const int om0 = bx * 128;                                   // out row base
    const int n0 = blockIdx.y * 128;

    int rS[4], kS[4];
#pragma unroll
    for (int j = 0; j < 4; ++j) {
        const int s = tid + 256 * j;
        rS[j] = s >> 3;
        kS[j] = (s & 7) ^ (rS[j] & 7);
    }
    const __bf16* Agp[4];
    const __bf16* Bgp[4];
#pragma unroll
    for (int j = 0; j < 4; ++j) {
        Agp[j] = A  + (size_t)(gm0 + rS[j]) * K + kS[j] * 8;
        Bgp[j] = Bt + (size_t)(n0 + rS[j]) * K + kS[j] * 8;
    }

    const int lane = tid & 63;
    const int wave = tid >> 6;
    const int wrow = (wave >> 1) * 64;
    const int wcol = (wave & 1) * 64;
    const int quad = lane >> 4;
    const int r = lane & 15;

    f32x4 acc[4][4] = {};

    const int T = K >> 6;            // K-tiles of 64 (T=32 for K=2048)

    auto stage = [&](int t, int b) {
        const int kt = t << 6;
#pragma unroll
        for (int j = 0; j < 4; ++j)
            async_ld16(Agp[j] + kt, sm.kl[b].A + (tid + 256 * j) * 8);
#pragma unroll
        for (int j = 0; j < 4; ++j)
            async_ld16(Bgp[j] + kt, sm.kl[b].B + (tid + 256 * j) * 8);
    };

    stage(0, 0);                     // 8 outstanding

    const int swz0 = ((0 * 4 + quad) ^ (r & 7)) * 8;
    const int swz1 = ((1 * 4 + quad) ^ (r & 7)) * 8;

    for (int t = 0; t < T; ++t) {
        const int cur = t & 1;
        if (t + 1 < T) {
            stage(t + 1, cur ^ 1);   // 16 outstanding
            asm volatile("s_waitcnt vmcnt(8)\n\ts_barrier" ::: "memory");
        } else {
            asm volatile("s_waitcnt vmcnt(0)\n\ts_barrier" ::: "memory");
        }

        const __bf16* apb = sm.kl[cur].A + (wrow + r) * 64;
        const __bf16* bpb = sm.kl[cur].B + (wcol + r) * 64;

#pragma unroll
        for (int ks = 0; ks < 2; ++ks) {
            const int swz = ks ? swz1 : swz0;
            bf16x8 af[4], bf_[4];
#pragma unroll
            for (int m = 0; m < 4; ++m)
                af[m] = *(const bf16x8*)(apb + m * 1024 + swz);
#pragma unroll
            for (int n = 0; n < 4; ++n)
                bf_[n] = *(const bf16x8*)(bpb + n * 1024 + swz);

            __builtin_amdgcn_s_setprio(1);
#pragma unroll
            for (int m = 0; m < 4; ++m)
#pragma unroll
                for (int n = 0; n < 4; ++n)
                    acc[m][n] = __builtin_amdgcn_mfma_f32_16x16x32_bf16(
                        af[m], bf_[n], acc[m][n], 0, 0, 0);
            __builtin_amdgcn_s_setprio(0);
        }

        asm volatile("s_waitcnt lgkmcnt(0)\n\ts_barrier" ::: "memory");
    }

    // fp32 staged epilogue: 4 passes of 32 rows through [32][132] LDS.
    {
        float bvj[4];
#pragma unroll
        for (int j = 0; j < 4; ++j)
            bvj[j] = bias[n0 + wcol + j * 16 + r];
#pragma unroll
        for (int p = 0; p < 4; ++p) {
#pragma unroll
            for (int j = 0; j < 4; ++j)
#pragma unroll
                for (int k = 0; k < 4; ++k)
                    sm.ctf[((wave >> 1) * 16 + quad * 4 + k) * 132 +
                           (wcol + j * 16 + r)] = acc[p][j][k] + bvj[j];
            __syncthreads();
#pragma unroll
            for (int q = 0; q < 4; ++q) {
                const int chunk = q * 256 + tid;      // 0..1023
                const int trow = chunk >> 5;          // 0..31
                const int tc4 = (chunk & 31) * 4;     // fp32 col, x4 chunk
                const f32x4 vv = *(const f32x4*)(sm.ctf + trow * 132 + tc4);
                const int grow = om0 + (trow >> 4) * 64 + p * 16 + (trow & 15);
                *(f32x4*)((float*)out + (size_t)grow * N + n0 + tc4) = vv;
            }
            __syncthreads();
        }
    }
}

// Parallel minGRU scan over one chunk, on raw pre-activations:
// z = sigmoid(raw_z), b = z * raw_h, h = (1-z)h + b.
// raw is [B*CS][4096] (z cols 0..2047, h cols 2048..4095).
#define SSEG 32
#define SCOLS 32
__global__ __launch_bounds__(1024)
void scan_kernel(const __bf16* __restrict__ raw, __bf16* __restrict__ xskip,
                 float* __restrict__ carry, int CS, int S, int t0, int first)
{
    __shared__ float Als[SSEG][SCOLS];
    __shared__ float Bls[SSEG][SCOLS];
    const int lane = threadIdx.x & (SCOLS - 1);   // col within group
    const int w = threadIdx.x >> 5;               // segment 0..31
    const int nb8 = gridDim.x >> 3;
    const int lin = (blockIdx.x & 7) * nb8 + (blockIdx.x >> 3);
    const int gpb = 2048 / SCOLS;                 // 64 groups per batch
    const int batch = lin / gpb;
    const int col = (lin - batch * gpb) * SCOLS + lane;
    const int L = CS / SSEG;                      // 32 (CS always 1024)
    const int tbeg = w * L;

    const size_t rbase = ((size_t)batch * CS + tbeg) * 4096 + col;

    float av[32], bv[32];
    float A = 1.0f, Bv = 0.0f;
    {
        size_t idx = rbase;
#pragma unroll
        for (int t = 0; t < 32; ++t, idx += 4096) {
            const float z = fsigmoid((float)raw[idx]);
            const float b = z * (float)raw[idx + 2048];
            const float a = 1.0f - z;
            av[t] = a;
            bv[t] = b;
            Bv = a * Bv + b;
            A *= a;
        }
    }
    Als[w][lane] = A;
    Bls[w][lane] = Bv;
    __syncthreads();

    const int ch = batch * 2048 + col;
    float h = first ? 0.0f : carry[ch];
    for (int s = 0; s < w; ++s)
        h = Als[s][lane] * h + Bls[s][lane];
    if (w == SSEG - 1)
        carry[ch] = A * h + Bv;

    {
        size_t gidx = ((size_t)batch * S + t0 + tbeg) * 2048 + col;
#pragma unroll
        for (int t = 0; t < 32; ++t, gidx += 2048) {
            h = av[t] * h + bv[t];
            xskip[gidx] = (__bf16)((float)xskip[gidx] + h);
        }
    }
}

// ---------------------------------------------------------------------------
// prep_kernel: fused prepass. Block-range dispatch (branch is block-uniform):
//   [0, 8192)            conv x fp32 -> xb bf16 (float4 granularity)
//   [8192, 8192+2048)    Wt12: transpose W_in1/W_in2 (K=512,  N=2048), z=hi
//   [+2048, +2048+8192)  Wtzh: transpose W_z/W_h    (K=2048, N=2048), z=hi
//   [.., +1024)          Wto:  transpose W_out      (K=2048, N=512)
// ---------------------------------------------------------------------------
__global__ __launch_bounds__(256)
void prep_kernel(const float* __restrict__ x, __bf16* __restrict__ xb,
                 const float* __restrict__ W_in1, const float* __restrict__ W_in2,
                 __bf16* __restrict__ Wt12,
                 const float* __restrict__ W_z, const float* __restrict__ W_h,
                 __bf16* __restrict__ Wtzh,
                 const float* __restrict__ W_out, __bf16* __restrict__ Wto)
{
    __shared__ float tile[32][33];
    int bid = blockIdx.x;
    if (bid < 8192) {                      // conv: 8192*256 float4 = M*H
        const int i = bid * 256 + threadIdx.x;
        const float4 v = ((const float4*)x)[i];
        bf16x4 o;
        o[0] = (__bf16)v.x; o[1] = (__bf16)v.y;
        o[2] = (__bf16)v.z; o[3] = (__bf16)v.w;
        ((bf16x4*)xb)[i] = o;
        return;
    }
    bid -= 8192;
    const float* W;
    __bf16* dst;
    int K, N, nb, kb;
    if (bid < 2048) {                      // Wt12 (K=512, N=2048)
        const int z = bid >> 10, rem = bid & 1023;
        W = z ? W_in2 : W_in1;
        dst = Wt12 + (size_t)z * 512 * 2048;
        K = 512; N = 2048;
        nb = (rem & 63) * 32; kb = (rem >> 6) * 32;   // rem = kb*64 + nb
    } else if (bid < 2048 + 8192) {        // Wtzh (K=2048, N=2048)
        const int b2 = bid - 2048;
        const int z = b2 >> 12, rem = b2 & 4095;
        W = z ? W_h : W_z;
        dst = Wtzh + (size_t)z * 2048 * 2048;
        K = 2048; N = 2048;
        nb = (rem & 63) * 32; kb = (rem >> 6) * 32;
    } else {                               // Wto (K=2048, N=512)
        const int b3 = bid - (2048 + 8192);
        W = W_out; dst = Wto;
        K = 2048; N = 512;
        nb = (b3 & 15) * 32; kb = (b3 >> 4) * 32;
    }
    const int tx = threadIdx.x & 31;
    const int ty = threadIdx.x >> 5;
#pragma unroll
    for (int i = 0; i < 32; i += 8)
        tile[ty + i][tx] = W[(size_t)(kb + ty + i) * N + nb + tx];
    __syncthreads();
#pragma unroll
    for (int i = 0; i < 32; i += 8)
        dst[(size_t)(nb + ty + i) * K + kb + tx] = (__bf16)tile[tx][ty + i];
}

extern "C" void kernel_launch(void* const* d_in, const int* in_sizes, int n_in,
                              void* d_out, int out_size, void* d_ws, size_t ws_size,
                              hipStream_t stream)
{
    const float* x     = (const float*)d_in[0];
    const float* W_in1 = (const float*)d_in[1];
    const float* b_in1 = (const float*)d_in[2];
    const float* W_in2 = (const float*)d_in[3];
    const float* b_in2 = (const float*)d_in[4];
    const float* W_z   = (const float*)d_in[5];
    const float* b_z   = (const float*)d_in[6];
    const float* W_h   = (const float*)d_in[7];
    const float* b_h   = (const float*)d_in[8];
    const float* W_out = (const float*)d_in[9];
    const float* b_out = (const float*)d_in[10];

    const int B = 4, S = 4096, H = 512, E = 2048;
    const int M = B * S;        // 16384
    const int CS = 1024;        // chunk length
    const int NC = S / CS;      // 4 chunks
    const int MC = B * CS;      // 4096 rows per chunk

    const size_t MiB = 1024 * 1024;
    const size_t NEEDED = 183 * MiB;
    if (ws_size < NEEDED) return;

    char* ws = (char*)d_ws;
    __bf16* xb    = (__bf16*)(ws + 0);        // overlaid by rawzh after use
    __bf16* rawzh = (__bf16*)(ws + 0);
    float*  carry = (float*) (ws + 32 * MiB);
    __bf16* xin   = (__bf16*)(ws + 33 * MiB);
    __bf16* xskip = (__bf16*)(ws + 97 * MiB);
    __bf16* Wt12  = (__bf16*)(ws + 161 * MiB);
    __bf16* Wtzh  = (__bf16*)(ws + 165 * MiB);
    __bf16* Wto   = (__bf16*)(ws + 181 * MiB);

    // Fused prepass: conv + all 5 weight transposes in one launch.
    prep_kernel<<<8192 + 2048 + 8192 + 1024, 256, 0, stream>>>(
        x, xb, W_in1, W_in2, Wt12, W_z, W_h, Wtzh, W_out, Wto);

    // Merged input GEMM: N=4096 (W1|W2), split-silu epilogue -> xin / xskip
    // gemm4 128x256 tiles, BK=32, 3 blk/CU: grid 128 x 16.
    gemm4<0><<<dim3(M / 128, 2 * E / 256), 512, 0, stream>>>(
        xb, Wt12, b_in1, b_in2, xin, xskip, 2 * E, H, M / 128, 0, 0);

    // Recurrent stage, chunked over S (rawzh overlays dead xb)
    // gemm3k (R20 4-phase + spread stagelets) 256^2, BK=64: grid 16x16, T=32.
    for (int c = 0; c < NC; ++c) {
        const int row_off = c * CS;
        gemm3k<4><<<dim3(MC / 256, 2 * E / 256), 512, 0, stream>>>(
            xin, Wtzh, b_z, b_h, rawzh, nullptr, 2 * E, E, CS / 256, S, row_off);
        scan_kernel<<<(B * E) / SCOLS, 1024, 0, stream>>>(
            rawzh, xskip, carry, CS, S, row_off, c == 0);
    }

    // Output GEMM (full M), fp32 out -- BK=64 (K=2048, T=32), grid 512 = 2/CU.
    gemm_bt64<3><<<dim3(M / 128, H / 128), 256, 0, stream>>>(
        xskip, Wto, b_out, nullptr, (float*)d_out, nullptr, H, E, M / 128, 0, 0);
}